// Round 1
// baseline (359.531 us; speedup 1.0000x reference)
//
#include <hip/hip_runtime.h>

// Problem constants
// x:    (2, 768, 8,8,8)   -> (2,768,512)
// out:  (2, 48, 64,64,64) -> (2,48,262144)
// output: (2, 32, 64,64,64)
constexpr int NCLS = 32;

// ws float offsets
constexpr int WS_GN1 = 0;       // 32 groups * {mean, rstd}
constexpr int WS_POOL = 64;     // 2*768
constexpr int WS_XF  = 1600;    // 2*256
constexpr int WS_PAR = 2112;    // 2*32*153 = 9792
constexpr int WS_P2  = 11904;   // 768 blocks * {sum,sumsq}
constexpr int WS_SS  = 13440;   // 2*48 * {scale,shift}

__device__ __forceinline__ float wred(float v) {
#pragma unroll
  for (int off = 32; off > 0; off >>= 1) v += __shfl_down(v, off, 64);
  return v;
}

// K1: GN1 stats. 32 blocks x 256 thr, one block per (b,group); group chunk = 48*512 = 24576 floats contiguous.
__global__ void k_gn1_stats(const float* __restrict__ x, float* __restrict__ ws) {
  int grp = blockIdx.x;
  const float4* p = reinterpret_cast<const float4*>(x + grp * 24576);
  float s = 0.f, s2 = 0.f;
#pragma unroll
  for (int k = 0; k < 24; ++k) {
    float4 v = p[k * 256 + threadIdx.x];
    s  += v.x + v.y + v.z + v.w;
    s2 += v.x*v.x + v.y*v.y + v.z*v.z + v.w*v.w;
  }
  s = wred(s); s2 = wred(s2);
  __shared__ float red[8];
  int wid = threadIdx.x >> 6, lane = threadIdx.x & 63;
  if (lane == 0) { red[wid*2] = s; red[wid*2+1] = s2; }
  __syncthreads();
  if (threadIdx.x == 0) {
    float S  = red[0]+red[2]+red[4]+red[6];
    float S2 = red[1]+red[3]+red[5]+red[7];
    float mean = S * (1.f/24576.f);
    float var  = S2 * (1.f/24576.f) - mean*mean;
    ws[WS_GN1 + grp*2]   = mean;
    ws[WS_GN1 + grp*2+1] = rsqrtf(var + 1e-5f);
  }
}

// K5: GN2 partial sums. 768 blocks (24 per (b,group)) x 256 thr; each block covers 32768 contiguous floats.
__global__ void k_gn2_part(const float* __restrict__ o, float* __restrict__ ws) {
  int blk = blockIdx.x;
  const float4* p = reinterpret_cast<const float4*>(o + (size_t)blk * 32768);
  float s = 0.f, s2 = 0.f;
#pragma unroll
  for (int k = 0; k < 32; ++k) {
    float4 v = p[k * 256 + threadIdx.x];
    s  += v.x + v.y + v.z + v.w;
    s2 += v.x*v.x + v.y*v.y + v.z*v.z + v.w*v.w;
  }
  s = wred(s); s2 = wred(s2);
  __shared__ float red[8];
  int wid = threadIdx.x >> 6, lane = threadIdx.x & 63;
  if (lane == 0) { red[wid*2] = s; red[wid*2+1] = s2; }
  __syncthreads();
  if (threadIdx.x == 0) {
    ws[WS_P2 + blk*2]   = red[0]+red[2]+red[4]+red[6];
    ws[WS_P2 + blk*2+1] = red[1]+red[3]+red[5]+red[7];
  }
}

// K2: pooled[b,c] = mean_s relu(gn1(x)). One wave per channel; 1536 channels -> 384 blocks.
__global__ void k_pooled(const float* __restrict__ x, const float* __restrict__ g1,
                         const float* __restrict__ b1, float* __restrict__ ws) {
  int wid = threadIdx.x >> 6, lane = threadIdx.x & 63;
  int ch = blockIdx.x * 4 + wid;          // [0,1536)
  int c = ch & 767;
  int grp = ch / 48;                      // == b*16 + c/48
  float mean = ws[WS_GN1 + grp*2], rstd = ws[WS_GN1 + grp*2+1];
  float sc = rstd * g1[c];
  float sh = b1[c] - mean * sc;
  const float* p = x + ch * 512;
  float s = 0.f;
#pragma unroll
  for (int i = 0; i < 8; ++i)
    s += fmaxf(fmaf(p[lane + i*64], sc, sh), 0.f);
  s = wred(s);
  if (lane == 0) ws[WS_POOL + ch] = s * (1.f/512.f);
}

// K3: x_feat[b,o] = pooled[b,:] . gap_w[o,:] + gap_b[o]. 512 outputs, one wave each.
__global__ void k_xfeat(const float* __restrict__ gap_w, const float* __restrict__ gap_b,
                        float* __restrict__ ws) {
  int wid = threadIdx.x >> 6, lane = threadIdx.x & 63;
  int idx = blockIdx.x * 4 + wid;         // [0,512)
  int b = idx >> 8, o = idx & 255;
  const float* pw = gap_w + o * 768;
  const float* pp = ws + WS_POOL + b * 768;
  float s = 0.f;
#pragma unroll
  for (int i = 0; i < 12; ++i) {
    int cc = lane + i*64;
    s += pw[cc] * pp[cc];
  }
  s = wred(s);
  if (lane == 0) ws[WS_XF + idx] = s + gap_b[o];
}

// K4: params[b,c,p] = ctrl_w[p,:256].x_feat[b] + ctrl_w[p,256:].te[c] + ctrl_b[p].
// 9792 entries, one wave each -> 2448 blocks.
__global__ void k_params(const float* __restrict__ ctrl_w, const float* __restrict__ ctrl_b,
                         const float* __restrict__ te, float* __restrict__ ws) {
  int wid = threadIdx.x >> 6, lane = threadIdx.x & 63;
  int e = blockIdx.x * 4 + wid;           // [0,9792)
  int b = e / (NCLS * 153);
  int r = e % (NCLS * 153);
  int c = r / 153, p = r % 153;
  const float* w  = ctrl_w + p * 512;
  const float* xf = ws + WS_XF + b * 256;
  const float* t  = te + c * 256;
  float s = 0.f;
#pragma unroll
  for (int i = 0; i < 4; ++i) {
    int f = lane + i*64;
    s += w[f] * xf[f] + w[256 + f] * t[f];
  }
  s = wred(s);
  if (lane == 0) ws[WS_PAR + e] = s + ctrl_b[p];
}

// K6: finalize GN2 mean/rstd (32 groups from 24 partials each), emit per-(b,c) scale/shift.
__global__ void k_gn2_fin(const float* __restrict__ g2, const float* __restrict__ b2,
                          float* __restrict__ ws) {
  __shared__ float ms[64];
  int t = threadIdx.x;  // 128 threads
  if (t < 32) {
    float S = 0.f, S2 = 0.f;
    for (int k = 0; k < 24; ++k) {
      S  += ws[WS_P2 + (t*24 + k)*2];
      S2 += ws[WS_P2 + (t*24 + k)*2 + 1];
    }
    float mean = S * (1.f/786432.f);
    float var  = S2 * (1.f/786432.f) - mean*mean;
    ms[t*2]   = mean;
    ms[t*2+1] = rsqrtf(var + 1e-5f);
  }
  __syncthreads();
  if (t < 96) {
    int b = t / 48, c = t - b*48;
    int grp = b*16 + c/3;
    float mean = ms[grp*2], rstd = ms[grp*2+1];
    float sc = rstd * g2[c];
    ws[WS_SS + t*2]   = sc;
    ws[WS_SS + t*2+1] = b2[c] - mean * sc;
  }
}

// K7: fused main. 2048 blocks x 256 thr; thread = one voxel of one batch.
// All weights indexed uniformly -> scalar loads, SGPR operands on v_fmac_f32.
__global__ __launch_bounds__(256) void k_main(const float* __restrict__ oin,
                                              const float* __restrict__ pre_w,
                                              const float* __restrict__ pre_b,
                                              const float* __restrict__ ws,
                                              float* __restrict__ out) {
  int b = blockIdx.x >> 10;
  int v = ((blockIdx.x & 1023) << 8) | threadIdx.x;
  const float* ip = oin + (size_t)b * (48 * 262144) + v;
  const float* ss = ws + WS_SS + b * 96;

  float vals[48];
#pragma unroll
  for (int c = 0; c < 48; ++c) vals[c] = ip[(size_t)c * 262144];

  float h0[8];
#pragma unroll
  for (int o = 0; o < 8; ++o) h0[o] = pre_b[o];
#pragma unroll
  for (int c = 0; c < 48; ++c) {
    float g = fmaxf(fmaf(vals[c], ss[c*2], ss[c*2+1]), 0.f);
#pragma unroll
    for (int o = 0; o < 8; ++o) h0[o] = fmaf(pre_w[o*48 + c], g, h0[o]);
  }

  const float* Pb = ws + WS_PAR + b * (NCLS * 153);
  float* op = out + (size_t)b * (NCLS * 262144) + v;
#pragma unroll 1
  for (int cls = 0; cls < NCLS; ++cls) {
    const float* W = Pb + cls * 153;
    float t1[8], t2[8];
#pragma unroll
    for (int i = 0; i < 8; ++i) {
      float a = W[136 + i];
#pragma unroll
      for (int j = 0; j < 8; ++j) a = fmaf(W[i*8 + j], h0[j], a);
      t1[i] = fmaxf(a, 0.f);
    }
#pragma unroll
    for (int i = 0; i < 8; ++i) {
      float a = W[144 + i];
#pragma unroll
      for (int j = 0; j < 8; ++j) a = fmaf(W[64 + i*8 + j], t1[j], a);
      t2[i] = fmaxf(a, 0.f);
    }
    float lg = W[152];
#pragma unroll
    for (int j = 0; j < 8; ++j) lg = fmaf(W[128 + j], t2[j], lg);
    op[(size_t)cls * 262144] = lg;
  }
}

extern "C" void kernel_launch(void* const* d_in, const int* in_sizes, int n_in,
                              void* d_out, int out_size, void* d_ws, size_t ws_size,
                              hipStream_t stream) {
  const float* x    = (const float*)d_in[0];
  const float* oin  = (const float*)d_in[1];
  const float* te   = (const float*)d_in[2];
  const float* g1   = (const float*)d_in[3];
  const float* b1   = (const float*)d_in[4];
  const float* gapw = (const float*)d_in[5];
  const float* gapb = (const float*)d_in[6];
  const float* cw   = (const float*)d_in[7];
  const float* cb   = (const float*)d_in[8];
  const float* g2   = (const float*)d_in[9];
  const float* b2   = (const float*)d_in[10];
  const float* prew = (const float*)d_in[11];
  const float* preb = (const float*)d_in[12];
  float* ws  = (float*)d_ws;
  float* out = (float*)d_out;

  hipLaunchKernelGGL(k_gn1_stats, dim3(32),   dim3(256), 0, stream, x, ws);
  hipLaunchKernelGGL(k_gn2_part,  dim3(768),  dim3(256), 0, stream, oin, ws);
  hipLaunchKernelGGL(k_pooled,    dim3(384),  dim3(256), 0, stream, x, g1, b1, ws);
  hipLaunchKernelGGL(k_xfeat,     dim3(128),  dim3(256), 0, stream, gapw, gapb, ws);
  hipLaunchKernelGGL(k_params,    dim3(2448), dim3(256), 0, stream, cw, cb, te, ws);
  hipLaunchKernelGGL(k_gn2_fin,   dim3(1),    dim3(128), 0, stream, g2, b2, ws);
  hipLaunchKernelGGL(k_main,      dim3(2048), dim3(256), 0, stream, oin, prew, preb, ws, out);
}

// Round 2
// 314.767 us; speedup vs baseline: 1.1422x; 1.1422x over previous
//
#include <hip/hip_runtime.h>

// x:    (2, 768, 8,8,8)   -> (2,768,512)
// out:  (2, 48, 64,64,64) -> (2,48,262144)
// output: (2, 32, 64,64,64)
constexpr int NCLS = 32;

// ws float offsets
constexpr int WS_POOL = 64;     // 2*768
constexpr int WS_PAR = 2112;    // 2*32*153 = 9792
constexpr int WS_P2  = 11904;   // 768 blocks * {sum,sumsq}

__device__ __forceinline__ float wred(float v) {
#pragma unroll
  for (int off = 32; off > 0; off >>= 1) v += __shfl_down(v, off, 64);
  return v;
}

// K3: GN2 partial sums. 768 blocks x 256 thr; each block covers 32768 contiguous floats.
__global__ void k_gn2_part(const float* __restrict__ o, float* __restrict__ ws) {
  int blk = blockIdx.x;
  const float4* p = reinterpret_cast<const float4*>(o + (size_t)blk * 32768);
  float s = 0.f, s2 = 0.f;
#pragma unroll
  for (int k = 0; k < 32; ++k) {
    float4 v = p[k * 256 + threadIdx.x];
    s  += v.x + v.y + v.z + v.w;
    s2 += v.x*v.x + v.y*v.y + v.z*v.z + v.w*v.w;
  }
  s = wred(s); s2 = wred(s2);
  __shared__ float red[8];
  int wid = threadIdx.x >> 6, lane = threadIdx.x & 63;
  if (lane == 0) { red[wid*2] = s; red[wid*2+1] = s2; }
  __syncthreads();
  if (threadIdx.x == 0) {
    ws[WS_P2 + blk*2]   = red[0]+red[2]+red[4]+red[6];
    ws[WS_P2 + blk*2+1] = red[1]+red[3]+red[5]+red[7];
  }
}

// K1: GN1 stats + pooled, fused. 32 blocks, one per (b,group). Group chunk = 48*512 floats contiguous.
__global__ void k1_gn1_pool(const float* __restrict__ x, const float* __restrict__ g1,
                            const float* __restrict__ b1, float* __restrict__ ws) {
  int g = blockIdx.x;                      // b = g>>4, grp = g&15
  int t = threadIdx.x;
  const float4* p = reinterpret_cast<const float4*>(x + g * 24576);
  float s = 0.f, s2 = 0.f;
#pragma unroll
  for (int k = 0; k < 24; ++k) {
    float4 v = p[k * 256 + t];
    s  += v.x + v.y + v.z + v.w;
    s2 += v.x*v.x + v.y*v.y + v.z*v.z + v.w*v.w;
  }
  s = wred(s); s2 = wred(s2);
  __shared__ float red[8];
  __shared__ float mstat[2];
  int wid = t >> 6, lane = t & 63;
  if (lane == 0) { red[wid*2] = s; red[wid*2+1] = s2; }
  __syncthreads();
  if (t == 0) {
    float S  = red[0]+red[2]+red[4]+red[6];
    float S2 = red[1]+red[3]+red[5]+red[7];
    float mean = S * (1.f/24576.f);
    float var  = S2 * (1.f/24576.f) - mean*mean;
    mstat[0] = mean; mstat[1] = rsqrtf(var + 1e-5f);
  }
  __syncthreads();
  float mean = mstat[0], rstd = mstat[1];
  // pooled: 48 channels, wave w takes channels k*4+w
#pragma unroll
  for (int k = 0; k < 12; ++k) {
    int i = k*4 + wid;                     // channel within group [0,48)
    int c = (g & 15) * 48 + i;             // channel [0,768)
    float sc = rstd * g1[c];
    float sh = b1[c] - mean * sc;
    const float* q = x + g * 24576 + i * 512;
    float acc = 0.f;
#pragma unroll
    for (int j = 0; j < 8; ++j)
      acc += fmaxf(fmaf(q[lane + j*64], sc, sh), 0.f);
    acc = wred(acc);
    if (lane == 0) ws[WS_POOL + (g >> 4) * 768 + c] = acc * (1.f/512.f);
  }
}

// K2: xfeat (redundant per block) + params. 64 blocks = (b,cls).
__global__ void k2_params(const float* __restrict__ gapw, const float* __restrict__ gapb,
                          const float* __restrict__ cw, const float* __restrict__ cb,
                          const float* __restrict__ te, float* __restrict__ ws) {
  int b = blockIdx.x >> 5, cls = blockIdx.x & 31;
  int t = threadIdx.x;
  __shared__ __align__(16) float pl[768];
  __shared__ __align__(16) float tl[256];
  __shared__ __align__(16) float xl[256];
  pl[t] = ws[WS_POOL + b*768 + t];
  pl[t+256] = ws[WS_POOL + b*768 + t + 256];
  pl[t+512] = ws[WS_POOL + b*768 + t + 512];
  tl[t] = te[cls*256 + t];
  __syncthreads();
  // x_feat[t] = pooled . gap_w[t,:] + gap_b[t]   (no relu in ref)
  {
    float acc = gapb[t];
    const float4* w4 = reinterpret_cast<const float4*>(gapw) + t * 192;
    const float4* p4 = reinterpret_cast<const float4*>(pl);
#pragma unroll 4
    for (int jj = 0; jj < 192; ++jj) {
      float4 w = w4[jj], p = p4[jj];
      acc = fmaf(w.x, p.x, acc); acc = fmaf(w.y, p.y, acc);
      acc = fmaf(w.z, p.z, acc); acc = fmaf(w.w, p.w, acc);
    }
    xl[t] = acc;
  }
  __syncthreads();
  if (t < 153) {
    float a = cb[t];
    const float4* c4 = reinterpret_cast<const float4*>(cw) + t * 128;
    const float4* x4 = reinterpret_cast<const float4*>(xl);
    const float4* t4 = reinterpret_cast<const float4*>(tl);
#pragma unroll 4
    for (int jj = 0; jj < 64; ++jj) {
      float4 w = c4[jj], v = x4[jj];
      a = fmaf(w.x, v.x, a); a = fmaf(w.y, v.y, a);
      a = fmaf(w.z, v.z, a); a = fmaf(w.w, v.w, a);
    }
#pragma unroll 4
    for (int jj = 0; jj < 64; ++jj) {
      float4 w = c4[64 + jj], v = t4[jj];
      a = fmaf(w.x, v.x, a); a = fmaf(w.y, v.y, a);
      a = fmaf(w.z, v.z, a); a = fmaf(w.w, v.w, a);
    }
    ws[WS_PAR + (b*NCLS + cls)*153 + t] = a;
  }
}

// K4: fused GN2-finalize + main head. 512 blocks x 256 thr; thread = 4 voxels (float4).
// Per-class weights staged in LDS with 160-float stride (16B-aligned rows -> ds_read_b128 broadcast).
__global__ __launch_bounds__(256) void k4_main(const float* __restrict__ oin,
                                               const float* __restrict__ prew,
                                               const float* __restrict__ preb,
                                               const float* __restrict__ g2,
                                               const float* __restrict__ b2,
                                               const float* __restrict__ ws,
                                               float* __restrict__ out) {
  __shared__ __align__(16) float Wl[NCLS * 160];
  __shared__ float prewT[384];
  __shared__ float2 ssl[48];
  __shared__ float ms[64];
  int t = threadIdx.x;
  int b = blockIdx.x >> 8, tile = blockIdx.x & 255;

  // finalize GN2 stats from 768 partials (24 per group)
  if (t < 32) {
    float S = 0.f, S2 = 0.f;
#pragma unroll
    for (int k = 0; k < 24; ++k) {
      S  += ws[WS_P2 + (t*24 + k)*2];
      S2 += ws[WS_P2 + (t*24 + k)*2 + 1];
    }
    float mean = S * (1.f/786432.f);
    float var  = S2 * (1.f/786432.f) - mean*mean;
    ms[t*2] = mean; ms[t*2+1] = rsqrtf(var + 1e-5f);
  }
  // stage pre_w transposed: prewT[c*8+o] = prew[o*48+c]
  if (t < 128) {
#pragma unroll
    for (int k = 0; k < 3; ++k) {
      int i = t + k*128;
      prewT[(i % 48) * 8 + (i / 48)] = prew[i];
    }
  }
  // stage this b's params, class stride padded 153 -> 160
  {
    const float* wsrc = ws + WS_PAR + b * (NCLS*153);
#pragma unroll 4
    for (int cc = 0; cc < NCLS; ++cc)
      if (t < 153) Wl[cc*160 + t] = wsrc[cc*153 + t];
  }
  __syncthreads();
  if (t < 48) {
    int grp = (b << 4) + t / 3;
    float mean = ms[grp*2], rstd = ms[grp*2+1];
    float sc = rstd * g2[t];
    ssl[t] = make_float2(sc, b2[t] - mean * sc);
  }
  __syncthreads();

  // h0 for 4 voxels
  const float4* ip4 = reinterpret_cast<const float4*>(oin) + (size_t)b * 48 * 65536 + tile*256 + t;
  float4 h0[8];
#pragma unroll
  for (int o = 0; o < 8; ++o) { float pb = preb[o]; h0[o] = make_float4(pb, pb, pb, pb); }
#pragma unroll
  for (int c = 0; c < 48; ++c) {
    float4 v = ip4[(size_t)c * 65536];
    float2 ss = ssl[c];
    float4 g;
    g.x = fmaxf(fmaf(v.x, ss.x, ss.y), 0.f);
    g.y = fmaxf(fmaf(v.y, ss.x, ss.y), 0.f);
    g.z = fmaxf(fmaf(v.z, ss.x, ss.y), 0.f);
    g.w = fmaxf(fmaf(v.w, ss.x, ss.y), 0.f);
#pragma unroll
    for (int o = 0; o < 8; ++o) {
      float w = prewT[c*8 + o];
      h0[o].x = fmaf(w, g.x, h0[o].x);
      h0[o].y = fmaf(w, g.y, h0[o].y);
      h0[o].z = fmaf(w, g.z, h0[o].z);
      h0[o].w = fmaf(w, g.w, h0[o].w);
    }
  }

  float4* op4 = reinterpret_cast<float4*>(out) + (size_t)b * NCLS * 65536 + tile*256 + t;
#pragma unroll 1
  for (int cls = 0; cls < NCLS; ++cls) {
    const float* W = Wl + cls * 160;
    float4 t1[8], t2[8];
#pragma unroll
    for (int i = 0; i < 8; ++i) {
      float bias = W[136 + i];
      float4 a = make_float4(bias, bias, bias, bias);
#pragma unroll
      for (int j = 0; j < 8; ++j) {
        float w = W[i*8 + j];
        a.x = fmaf(w, h0[j].x, a.x); a.y = fmaf(w, h0[j].y, a.y);
        a.z = fmaf(w, h0[j].z, a.z); a.w = fmaf(w, h0[j].w, a.w);
      }
      t1[i].x = fmaxf(a.x, 0.f); t1[i].y = fmaxf(a.y, 0.f);
      t1[i].z = fmaxf(a.z, 0.f); t1[i].w = fmaxf(a.w, 0.f);
    }
#pragma unroll
    for (int i = 0; i < 8; ++i) {
      float bias = W[144 + i];
      float4 a = make_float4(bias, bias, bias, bias);
#pragma unroll
      for (int j = 0; j < 8; ++j) {
        float w = W[64 + i*8 + j];
        a.x = fmaf(w, t1[j].x, a.x); a.y = fmaf(w, t1[j].y, a.y);
        a.z = fmaf(w, t1[j].z, a.z); a.w = fmaf(w, t1[j].w, a.w);
      }
      t2[i].x = fmaxf(a.x, 0.f); t2[i].y = fmaxf(a.y, 0.f);
      t2[i].z = fmaxf(a.z, 0.f); t2[i].w = fmaxf(a.w, 0.f);
    }
    float b3v = W[152];
    float4 lg = make_float4(b3v, b3v, b3v, b3v);
#pragma unroll
    for (int j = 0; j < 8; ++j) {
      float w = W[128 + j];
      lg.x = fmaf(w, t2[j].x, lg.x); lg.y = fmaf(w, t2[j].y, lg.y);
      lg.z = fmaf(w, t2[j].z, lg.z); lg.w = fmaf(w, t2[j].w, lg.w);
    }
    op4[(size_t)cls * 65536] = lg;
  }
}

extern "C" void kernel_launch(void* const* d_in, const int* in_sizes, int n_in,
                              void* d_out, int out_size, void* d_ws, size_t ws_size,
                              hipStream_t stream) {
  const float* x    = (const float*)d_in[0];
  const float* oin  = (const float*)d_in[1];
  const float* te   = (const float*)d_in[2];
  const float* g1   = (const float*)d_in[3];
  const float* b1   = (const float*)d_in[4];
  const float* gapw = (const float*)d_in[5];
  const float* gapb = (const float*)d_in[6];
  const float* cw   = (const float*)d_in[7];
  const float* cb   = (const float*)d_in[8];
  const float* g2   = (const float*)d_in[9];
  const float* b2   = (const float*)d_in[10];
  const float* prew = (const float*)d_in[11];
  const float* preb = (const float*)d_in[12];
  float* ws  = (float*)d_ws;
  float* out = (float*)d_out;

  hipLaunchKernelGGL(k_gn2_part,  dim3(768), dim3(256), 0, stream, oin, ws);
  hipLaunchKernelGGL(k1_gn1_pool, dim3(32),  dim3(256), 0, stream, x, g1, b1, ws);
  hipLaunchKernelGGL(k2_params,   dim3(64),  dim3(256), 0, stream, gapw, gapb, cw, cb, te, ws);
  hipLaunchKernelGGL(k4_main,     dim3(512), dim3(256), 0, stream, oin, prew, preb, g2, b2, ws, out);
}

// Round 3
// 284.061 us; speedup vs baseline: 1.2657x; 1.1081x over previous
//
#include <hip/hip_runtime.h>

// x:    (2, 768, 8,8,8)   -> (2,768,512)
// out:  (2, 48, 64,64,64) -> (2,48,262144)
// output: (2, 32, 64,64,64)
constexpr int NCLS = 32;

// ws float offsets
constexpr int WS_POOL = 64;     // 2*768
constexpr int WS_XF  = 1600;    // 2*256
constexpr int WS_PAR = 2112;    // 2*32*153 = 9792
constexpr int WS_P2  = 11904;   // 768 blocks * {sum,sumsq}

__device__ __forceinline__ float wred(float v) {
#pragma unroll
  for (int off = 32; off > 0; off >>= 1) v += __shfl_down(v, off, 64);
  return v;
}

__device__ __forceinline__ float4 fma4(float w, float4 v, float4 a) {
  a.x = fmaf(w, v.x, a.x); a.y = fmaf(w, v.y, a.y);
  a.z = fmaf(w, v.z, a.z); a.w = fmaf(w, v.w, a.w);
  return a;
}
__device__ __forceinline__ float4 relu4(float4 a) {
  a.x = fmaxf(a.x, 0.f); a.y = fmaxf(a.y, 0.f);
  a.z = fmaxf(a.z, 0.f); a.w = fmaxf(a.w, 0.f);
  return a;
}
__device__ __forceinline__ float4 bcast4(float v) { return make_float4(v, v, v, v); }

// K1: 800 blocks. Blocks 0..767: GN2 partial sums (32768 contiguous floats each).
//     Blocks 768..799: GN1 stats + relu-mean pool for one (b,group) (24576 floats).
__global__ void k1_stats(const float* __restrict__ x, const float* __restrict__ oin,
                         const float* __restrict__ g1, const float* __restrict__ b1,
                         float* __restrict__ ws) {
  int t = threadIdx.x;
  int wid = t >> 6, lane = t & 63;
  __shared__ float red[8];
  if (blockIdx.x < 768) {
    int blk = blockIdx.x;
    const float4* p = reinterpret_cast<const float4*>(oin + (size_t)blk * 32768);
    float s = 0.f, s2 = 0.f;
#pragma unroll
    for (int k = 0; k < 32; ++k) {
      float4 v = p[k * 256 + t];
      s  += v.x + v.y + v.z + v.w;
      s2 += v.x*v.x + v.y*v.y + v.z*v.z + v.w*v.w;
    }
    s = wred(s); s2 = wred(s2);
    if (lane == 0) { red[wid*2] = s; red[wid*2+1] = s2; }
    __syncthreads();
    if (t == 0) {
      ws[WS_P2 + blk*2]   = red[0]+red[2]+red[4]+red[6];
      ws[WS_P2 + blk*2+1] = red[1]+red[3]+red[5]+red[7];
    }
  } else {
    int g = blockIdx.x - 768;              // b = g>>4, grp = g&15
    __shared__ float mstat[2];
    const float4* p = reinterpret_cast<const float4*>(x + g * 24576);
    float s = 0.f, s2 = 0.f;
#pragma unroll
    for (int k = 0; k < 24; ++k) {
      float4 v = p[k * 256 + t];
      s  += v.x + v.y + v.z + v.w;
      s2 += v.x*v.x + v.y*v.y + v.z*v.z + v.w*v.w;
    }
    s = wred(s); s2 = wred(s2);
    if (lane == 0) { red[wid*2] = s; red[wid*2+1] = s2; }
    __syncthreads();
    if (t == 0) {
      float S  = red[0]+red[2]+red[4]+red[6];
      float S2 = red[1]+red[3]+red[5]+red[7];
      float mean = S * (1.f/24576.f);
      float var  = S2 * (1.f/24576.f) - mean*mean;
      mstat[0] = mean; mstat[1] = rsqrtf(var + 1e-5f);
    }
    __syncthreads();
    float mean = mstat[0], rstd = mstat[1];
#pragma unroll
    for (int k = 0; k < 12; ++k) {
      int i = k*4 + wid;                   // channel within group [0,48)
      int c = (g & 15) * 48 + i;           // channel [0,768)
      float sc = rstd * g1[c];
      float sh = b1[c] - mean * sc;
      const float* q = x + g * 24576 + i * 512;
      float acc = 0.f;
#pragma unroll
      for (int j = 0; j < 8; ++j)
        acc += fmaxf(fmaf(q[lane + j*64], sc, sh), 0.f);
      acc = wred(acc);
      if (lane == 0) ws[WS_POOL + (g >> 4) * 768 + c] = acc * (1.f/512.f);
    }
  }
}

// K2: x_feat, wave-per-output (coalesced row reads). 512 outputs -> 128 blocks.
__global__ void k2_xfeat(const float* __restrict__ gapw, const float* __restrict__ gapb,
                         float* __restrict__ ws) {
  int wid = threadIdx.x >> 6, lane = threadIdx.x & 63;
  int idx = blockIdx.x * 4 + wid;          // [0,512)
  int b = idx >> 8, o = idx & 255;
  const float* pw = gapw + o * 768;
  const float* pp = ws + WS_POOL + b * 768;
  float s = 0.f;
#pragma unroll
  for (int i = 0; i < 12; ++i) {
    int cc = lane + i*64;
    s += pw[cc] * pp[cc];
  }
  s = wred(s);
  if (lane == 0) ws[WS_XF + idx] = s + gapb[o];
}

// K3: params, wave-per-output (coalesced). 9792 outputs -> 2448 blocks.
__global__ void k3_params(const float* __restrict__ cw, const float* __restrict__ cb,
                          const float* __restrict__ te, float* __restrict__ ws) {
  int wid = threadIdx.x >> 6, lane = threadIdx.x & 63;
  int e = blockIdx.x * 4 + wid;            // [0,9792)
  int b = e / (NCLS * 153);
  int r = e % (NCLS * 153);
  int c = r / 153, p = r % 153;
  const float* w  = cw + p * 512;
  const float* xf = ws + WS_XF + b * 256;
  const float* tv = te + c * 256;
  float s = 0.f;
#pragma unroll
  for (int i = 0; i < 4; ++i) {
    int f = lane + i*64;
    s += w[f] * xf[f] + w[256 + f] * tv[f];
  }
  s = wred(s);
  if (lane == 0) ws[WS_PAR + e] = s + cb[p];
}

// K4: fused GN2-finalize + main head. 256 blocks x 256 thr; thread = 8 voxels (2x float4).
// Per-class weights in LDS (160-float stride, 16B-aligned rows); each W row read once
// per class into regs and applied to both voxel groups.
__global__ __launch_bounds__(256) void k4_main(const float* __restrict__ oin,
                                               const float* __restrict__ prew,
                                               const float* __restrict__ preb,
                                               const float* __restrict__ g2,
                                               const float* __restrict__ b2,
                                               const float* __restrict__ ws,
                                               float* __restrict__ out) {
  __shared__ __align__(16) float Wl[NCLS * 160];
  __shared__ __align__(16) float prewT[384];
  __shared__ float2 ssl[48];
  __shared__ float ms[64];
  int t = threadIdx.x;
  int b = blockIdx.x >> 7, tile = blockIdx.x & 127;

  if (t < 32) {
    float S = 0.f, S2 = 0.f;
#pragma unroll
    for (int k = 0; k < 24; ++k) {
      S  += ws[WS_P2 + (t*24 + k)*2];
      S2 += ws[WS_P2 + (t*24 + k)*2 + 1];
    }
    float mean = S * (1.f/786432.f);
    float var  = S2 * (1.f/786432.f) - mean*mean;
    ms[t*2] = mean; ms[t*2+1] = rsqrtf(var + 1e-5f);
  }
  if (t < 128) {
#pragma unroll
    for (int k = 0; k < 3; ++k) {
      int i = t + k*128;
      prewT[(i % 48) * 8 + (i / 48)] = prew[i];
    }
  }
  {
    const float* wsrc = ws + WS_PAR + b * (NCLS*153);
#pragma unroll 4
    for (int cc = 0; cc < NCLS; ++cc)
      if (t < 153) Wl[cc*160 + t] = wsrc[cc*153 + t];
  }
  __syncthreads();
  if (t < 48) {
    int grp = (b << 4) + t / 3;
    float mean = ms[grp*2], rstd = ms[grp*2+1];
    float sc = rstd * g2[t];
    ssl[t] = make_float2(sc, b2[t] - mean * sc);
  }
  __syncthreads();

  // h0 for 8 voxels (two float4 groups, 1024B apart within block tile)
  const float4* ip4 = reinterpret_cast<const float4*>(oin)
                      + (size_t)b * 48 * 65536 + tile*512 + t;
  const float4* pT4 = reinterpret_cast<const float4*>(prewT);
  float4 h0a[8], h0b[8];
#pragma unroll
  for (int o = 0; o < 8; ++o) { float pb = preb[o]; h0a[o] = bcast4(pb); h0b[o] = bcast4(pb); }
#pragma unroll
  for (int c = 0; c < 48; ++c) {
    float4 va = ip4[(size_t)c * 65536];
    float4 vb = ip4[(size_t)c * 65536 + 256];
    float2 ss = ssl[c];
    float4 ga = relu4(make_float4(fmaf(va.x, ss.x, ss.y), fmaf(va.y, ss.x, ss.y),
                                  fmaf(va.z, ss.x, ss.y), fmaf(va.w, ss.x, ss.y)));
    float4 gb = relu4(make_float4(fmaf(vb.x, ss.x, ss.y), fmaf(vb.y, ss.x, ss.y),
                                  fmaf(vb.z, ss.x, ss.y), fmaf(vb.w, ss.x, ss.y)));
    float4 w0 = pT4[c*2], w1 = pT4[c*2+1];
    h0a[0] = fma4(w0.x, ga, h0a[0]); h0b[0] = fma4(w0.x, gb, h0b[0]);
    h0a[1] = fma4(w0.y, ga, h0a[1]); h0b[1] = fma4(w0.y, gb, h0b[1]);
    h0a[2] = fma4(w0.z, ga, h0a[2]); h0b[2] = fma4(w0.z, gb, h0b[2]);
    h0a[3] = fma4(w0.w, ga, h0a[3]); h0b[3] = fma4(w0.w, gb, h0b[3]);
    h0a[4] = fma4(w1.x, ga, h0a[4]); h0b[4] = fma4(w1.x, gb, h0b[4]);
    h0a[5] = fma4(w1.y, ga, h0a[5]); h0b[5] = fma4(w1.y, gb, h0b[5]);
    h0a[6] = fma4(w1.z, ga, h0a[6]); h0b[6] = fma4(w1.z, gb, h0b[6]);
    h0a[7] = fma4(w1.w, ga, h0a[7]); h0b[7] = fma4(w1.w, gb, h0b[7]);
  }

  float4* op4 = reinterpret_cast<float4*>(out)
                + (size_t)b * NCLS * 65536 + tile*512 + t;
#pragma unroll 1
  for (int cls = 0; cls < NCLS; ++cls) {
    const float4* W4 = reinterpret_cast<const float4*>(Wl + cls * 160);
    // biases / w3
    float4 b1q0 = W4[34], b1q1 = W4[35];     // b1[0..7]
    float4 b2q0 = W4[36], b2q1 = W4[37];     // b2[0..7]
    float4 w3q0 = W4[32], w3q1 = W4[33];     // w3[0..7]
    float b3v = W4[38].x;
    float b1arr[8] = {b1q0.x,b1q0.y,b1q0.z,b1q0.w,b1q1.x,b1q1.y,b1q1.z,b1q1.w};
    float b2arr[8] = {b2q0.x,b2q0.y,b2q0.z,b2q0.w,b2q1.x,b2q1.y,b2q1.z,b2q1.w};
    float w3arr[8] = {w3q0.x,w3q0.y,w3q0.z,w3q0.w,w3q1.x,w3q1.y,w3q1.z,w3q1.w};

    float4 t1a[8], t1b[8];
#pragma unroll
    for (int i = 0; i < 8; ++i) {
      float4 w0 = W4[i*2], w1 = W4[i*2+1];
      float4 aA = bcast4(b1arr[i]), aB = bcast4(b1arr[i]);
      aA = fma4(w0.x, h0a[0], aA); aB = fma4(w0.x, h0b[0], aB);
      aA = fma4(w0.y, h0a[1], aA); aB = fma4(w0.y, h0b[1], aB);
      aA = fma4(w0.z, h0a[2], aA); aB = fma4(w0.z, h0b[2], aB);
      aA = fma4(w0.w, h0a[3], aA); aB = fma4(w0.w, h0b[3], aB);
      aA = fma4(w1.x, h0a[4], aA); aB = fma4(w1.x, h0b[4], aB);
      aA = fma4(w1.y, h0a[5], aA); aB = fma4(w1.y, h0b[5], aB);
      aA = fma4(w1.z, h0a[6], aA); aB = fma4(w1.z, h0b[6], aB);
      aA = fma4(w1.w, h0a[7], aA); aB = fma4(w1.w, h0b[7], aB);
      t1a[i] = relu4(aA); t1b[i] = relu4(aB);
    }
    // layer2 + layer3 fused (t2 row consumed immediately)
    float4 lgA = bcast4(b3v), lgB = bcast4(b3v);
#pragma unroll
    for (int i = 0; i < 8; ++i) {
      float4 w0 = W4[16 + i*2], w1 = W4[17 + i*2];
      float4 aA = bcast4(b2arr[i]), aB = bcast4(b2arr[i]);
      aA = fma4(w0.x, t1a[0], aA); aB = fma4(w0.x, t1b[0], aB);
      aA = fma4(w0.y, t1a[1], aA); aB = fma4(w0.y, t1b[1], aB);
      aA = fma4(w0.z, t1a[2], aA); aB = fma4(w0.z, t1b[2], aB);
      aA = fma4(w0.w, t1a[3], aA); aB = fma4(w0.w, t1b[3], aB);
      aA = fma4(w1.x, t1a[4], aA); aB = fma4(w1.x, t1b[4], aB);
      aA = fma4(w1.y, t1a[5], aA); aB = fma4(w1.y, t1b[5], aB);
      aA = fma4(w1.z, t1a[6], aA); aB = fma4(w1.z, t1b[6], aB);
      aA = fma4(w1.w, t1a[7], aA); aB = fma4(w1.w, t1b[7], aB);
      aA = relu4(aA); aB = relu4(aB);
      lgA = fma4(w3arr[i], aA, lgA); lgB = fma4(w3arr[i], aB, lgB);
    }
    op4[(size_t)cls * 65536]       = lgA;
    op4[(size_t)cls * 65536 + 256] = lgB;
  }
}

extern "C" void kernel_launch(void* const* d_in, const int* in_sizes, int n_in,
                              void* d_out, int out_size, void* d_ws, size_t ws_size,
                              hipStream_t stream) {
  const float* x    = (const float*)d_in[0];
  const float* oin  = (const float*)d_in[1];
  const float* te   = (const float*)d_in[2];
  const float* g1   = (const float*)d_in[3];
  const float* b1   = (const float*)d_in[4];
  const float* gapw = (const float*)d_in[5];
  const float* gapb = (const float*)d_in[6];
  const float* cw   = (const float*)d_in[7];
  const float* cb   = (const float*)d_in[8];
  const float* g2   = (const float*)d_in[9];
  const float* b2   = (const float*)d_in[10];
  const float* prew = (const float*)d_in[11];
  const float* preb = (const float*)d_in[12];
  float* ws  = (float*)d_ws;
  float* out = (float*)d_out;

  hipLaunchKernelGGL(k1_stats,  dim3(800),  dim3(256), 0, stream, x, oin, g1, b1, ws);
  hipLaunchKernelGGL(k2_xfeat,  dim3(128),  dim3(256), 0, stream, gapw, gapb, ws);
  hipLaunchKernelGGL(k3_params, dim3(2448), dim3(256), 0, stream, cw, cb, te, ws);
  hipLaunchKernelGGL(k4_main,   dim3(256),  dim3(256), 0, stream, oin, prew, preb, g2, b2, ws, out);
}